// Round 2
// baseline (421.325 us; speedup 1.0000x reference)
//
#include <hip/hip_runtime.h>
#include <cstdint>
#include <cstddef>

#define CIN   128
#define COUT  256
#define HW    64
#define NSP   4096      // 64*64 spatial
#define KTOT  1152      // CIN*9
#define BATCH 32
#define PDROP 0.2f
#define LDT   40        // fallback conv LDS stride (bf16 elems)
#define LDT2  72        // v2 conv LDS stride: 64 data + 8 pad (16B-aligned rows)

__device__ __forceinline__ unsigned short f2bf(float f) {
    unsigned int u = __builtin_bit_cast(unsigned int, f);
    u += 0x7fffu + ((u >> 16) & 1u);   // round-to-nearest-even
    return (unsigned short)(u >> 16);
}

// ---------------------------------------------------------------------------
// Pre-pass 1: per-sample masked bf16 weights, tap-major: wt[bo][r*128+i]
// Coalesced float4 reads, LDS permute, coalesced uint4 writes.
__global__ __launch_bounds__(128) void mask_weights(
        const float* __restrict__ weight, const float* __restrict__ u_w,
        unsigned short* __restrict__ wt)
{
    __shared__ unsigned short tile[KTOT];
    const int bo = blockIdx.x;                 // b*COUT + o
    const int o  = bo & (COUT - 1);
    const int t  = threadIdx.x;
    const float4* wsrc = reinterpret_cast<const float4*>(weight + (size_t)o  * KTOT);
    const float4* usrc = reinterpret_cast<const float4*>(u_w    + (size_t)bo * KTOT);
    #pragma unroll
    for (int j = 0; j < 3; ++j) {
        const int idx = j * 128 + t;           // 0..287 float4s
        if (idx < KTOT / 4) {
            float4 wv = wsrc[idx];
            float4 uv = usrc[idx];
            const float w4[4] = {wv.x, wv.y, wv.z, wv.w};
            const float u4[4] = {uv.x, uv.y, uv.z, uv.w};
            #pragma unroll
            for (int c = 0; c < 4; ++c) {
                const int ks = idx * 4 + c;    // OIHW flat: ks = i*9 + r
                const int i  = ks / 9;
                const int r  = ks - 9 * i;
                tile[r * CIN + i] = f2bf((u4[c] > PDROP) ? w4[c] : 0.f);
            }
        }
    }
    __syncthreads();
    const uint4* src = reinterpret_cast<const uint4*>(tile);
    uint4* dst = reinterpret_cast<uint4*>(wt + (size_t)bo * KTOT);
    #pragma unroll
    for (int j = 0; j < 2; ++j) {
        const int idx = j * 128 + t;           // 0..143 uint4s
        if (idx < KTOT / 8) dst[idx] = src[idx];
    }
}

// ---------------------------------------------------------------------------
// Pre-pass 2: x NCHW fp32 -> xt[b][hw][ch] bf16 (NHWC).
__global__ __launch_bounds__(256) void transpose_x(
        const float* __restrict__ x, unsigned short* __restrict__ xt)
{
    __shared__ unsigned short tile[64 * 136];  // [hw_loc][ch], stride 136 (16B-aligned)
    const int b   = blockIdx.y;
    const int hw0 = blockIdx.x * 64;
    const int t   = threadIdx.x;
    // load: 128 ch x 64 hw fp32, coalesced float4 along hw
    const int ib  = t >> 4;                    // 0..15
    const int hw4 = (t & 15) * 4;
    #pragma unroll
    for (int j = 0; j < 8; ++j) {
        const int i = ib + 16 * j;             // channel 0..127
        const float4 v = *reinterpret_cast<const float4*>(
            x + ((size_t)(b * CIN + i)) * NSP + hw0 + hw4);
        const float v4[4] = {v.x, v.y, v.z, v.w};
        #pragma unroll
        for (int c = 0; c < 4; ++c)
            tile[(hw4 + c) * 136 + i] = f2bf(v4[c]);
    }
    __syncthreads();
    // store: 64 hw x 128 ch bf16, coalesced uint4 along ch
    #pragma unroll
    for (int j = 0; j < 4; ++j) {
        const int idx  = j * 256 + t;          // 0..1023
        const int row  = idx >> 4;             // hw_loc 0..63
        const int part = idx & 15;             // 16 B chunk 0..15
        const uint4 v = *reinterpret_cast<const uint4*>(&tile[row * 136 + part * 8]);
        *reinterpret_cast<uint4*>(
            xt + ((size_t)(b * NSP + hw0 + row)) * CIN + part * 8) = v;
    }
}

// ---------------------------------------------------------------------------
// Main conv v2: implicit GEMM, BM=BN=128, BK=64 (2 MFMA k-steps), 18 stages.
// A from wt (tap-major bf16), B from xt (NHWC bf16): all staging is b128.
__global__ __launch_bounds__(256) void conv_v2(
        const unsigned short* __restrict__ wt,
        const unsigned short* __restrict__ xt,
        const float* __restrict__ bias, const float* __restrict__ u_b,
        float* __restrict__ out)
{
    using frag  = __attribute__((ext_vector_type(8))) short;
    using f32x4 = __attribute__((ext_vector_type(4))) float;

    __shared__ unsigned short As[128 * LDT2];  // [o_loc][k]  18432 B
    __shared__ unsigned short Bs[128 * LDT2];  // [p_loc][k]  18432 B

    const int tid  = threadIdx.x;
    const int lane = tid & 63;
    const int q    = lane >> 4;
    const int l15  = lane & 15;
    const int wv   = tid >> 6;
    const int wm   = (wv >> 1) * 64;
    const int wn   = (wv & 1) * 64;

    const int b  = blockIdx.z;
    const int m0 = blockIdx.y * 128;
    const int n0 = blockIdx.x * 128;

    // staging map: 8 lanes cover one row's 128 B (8 x 16 B), 4 row-groups
    const int part = tid & 7;                  // 16 B chunk within row
    const int rowb = tid >> 3;                 // 0..31

    const unsigned short* wtb = wt + (size_t)(b * COUT + m0) * KTOT;
    const unsigned short* xtb = xt + (size_t)b * NSP * CIN;

    f32x4 acc[4][4];
    #pragma unroll
    for (int i = 0; i < 4; ++i)
        #pragma unroll
        for (int j = 0; j < 4; ++j)
            acc[i][j] = (f32x4){0.f, 0.f, 0.f, 0.f};

    const int a_rd = (wm + l15) * LDT2 + q * 8;
    const int b_rd = (wn + l15) * LDT2 + q * 8;

    for (int s = 0; s < 18; ++s) {
        const int r  = s >> 1;                 // tap 0..8 (wave-uniform)
        const int i0 = (s & 1) * 64;           // channel base
        const int k0 = s * 64;
        const int dy = r / 3 - 1;
        const int dx = r - 3 * (r / 3) - 1;

        // ---- global loads (regs; overlap previous stage's MFMA)
        uint4 av[4], bv[4];
        #pragma unroll
        for (int j = 0; j < 4; ++j) {
            const int row = rowb + 32 * j;
            av[j] = *reinterpret_cast<const uint4*>(
                wtb + (size_t)row * KTOT + k0 + part * 8);
            const int p  = n0 + row;
            const int hh = (p >> 6) + dy;
            const int ww = (p & 63) + dx;
            if (((unsigned)hh < 64u) && ((unsigned)ww < 64u)) {
                bv[j] = *reinterpret_cast<const uint4*>(
                    xtb + (size_t)(hh * HW + ww) * CIN + i0 + part * 8);
            } else {
                bv[j] = (uint4){0u, 0u, 0u, 0u};
            }
        }

        __syncthreads();                       // prior frag reads complete

        #pragma unroll
        for (int j = 0; j < 4; ++j) {
            const int row = rowb + 32 * j;
            *reinterpret_cast<uint4*>(&As[row * LDT2 + part * 8]) = av[j];
            *reinterpret_cast<uint4*>(&Bs[row * LDT2 + part * 8]) = bv[j];
        }

        __syncthreads();

        #pragma unroll
        for (int ki = 0; ki < 2; ++ki) {
            frag af[4], bfr[4];
            #pragma unroll
            for (int mi = 0; mi < 4; ++mi)
                af[mi] = *reinterpret_cast<const frag*>(
                    &As[a_rd + ki * 32 + mi * 16 * LDT2]);
            #pragma unroll
            for (int ni = 0; ni < 4; ++ni)
                bfr[ni] = *reinterpret_cast<const frag*>(
                    &Bs[b_rd + ki * 32 + ni * 16 * LDT2]);
            #pragma unroll
            for (int mi = 0; mi < 4; ++mi)
                #pragma unroll
                for (int ni = 0; ni < 4; ++ni)
                    acc[mi][ni] = __builtin_amdgcn_mfma_f32_16x16x32_bf16(
                        af[mi], bfr[ni], acc[mi][ni], 0, 0, 0);
        }
    }

    // ---- epilogue: D row=(q*4+reg), col=l15 ; add dropped-out bias
    float* ob = out + (size_t)b * COUT * NSP;
    #pragma unroll
    for (int mi = 0; mi < 4; ++mi) {
        #pragma unroll
        for (int rg = 0; rg < 4; ++rg) {
            const int o  = m0 + wm + mi * 16 + q * 4 + rg;
            const float bvv = (u_b[b * COUT + o] > PDROP) ? bias[o] : 0.f;
            float* orow = ob + (size_t)o * NSP + n0 + wn + l15;
            #pragma unroll
            for (int ni = 0; ni < 4; ++ni)
                orow[ni * 16] = acc[mi][ni][rg] + bvv;
        }
    }
}

// ---------------------------------------------------------------------------
// Fallback (round-1 kernel): used only if workspace is too small.
template<bool USE_WS>
__global__ __launch_bounds__(256) void conv_fb(
        const float* __restrict__ x, const float* __restrict__ weight,
        const float* __restrict__ bias, const float* __restrict__ u_w,
        const float* __restrict__ u_b, const unsigned short* __restrict__ wt,
        float* __restrict__ out)
{
    using frag  = __attribute__((ext_vector_type(8))) short;
    using f32x4 = __attribute__((ext_vector_type(4))) float;

    __shared__ unsigned short As[128 * LDT];
    __shared__ unsigned short Bs[128 * LDT];

    const int tid  = threadIdx.x;
    const int lane = tid & 63;
    const int q    = lane >> 4;
    const int l15  = lane & 15;
    const int wv   = tid >> 6;
    const int wm   = (wv >> 1) * 64;
    const int wn   = (wv & 1) * 64;

    const int b  = blockIdx.z;
    const int m0 = blockIdx.y * 128;
    const int n0 = blockIdx.x * 128;

    const int arow = tid >> 1;
    const int acol = (tid & 1) * 16;
    const int pn = tid & 127;
    const int kh = (tid >> 7) * 16;
    const int p  = n0 + pn;
    const int ph = p >> 6;
    const int pw = p & 63;

    const float* xb = x + (size_t)b * CIN * NSP;

    f32x4 acc[4][4];
    #pragma unroll
    for (int i = 0; i < 4; ++i)
        #pragma unroll
        for (int j = 0; j < 4; ++j)
            acc[i][j] = (f32x4){0.f, 0.f, 0.f, 0.f};

    const int a_rd = (wm + l15) * LDT + q * 8;
    const int b_rd = (wn + l15) * LDT + q * 8;

    for (int s = 0; s < 36; ++s) {
        const int r  = s >> 2;
        const int i0 = (s & 3) * 32;
        const int k0 = s * 32;

        uint4 av0, av1;
        float aw[16], au[16];
        if (USE_WS) {
            const uint4* src = reinterpret_cast<const uint4*>(
                wt + ((size_t)(b * COUT + m0 + arow)) * KTOT + k0 + acol);
            av0 = src[0];
            av1 = src[1];
        } else {
            const float* wsrc = weight + (size_t)(m0 + arow) * KTOT;
            const float* usrc = u_w + (size_t)(b * COUT + m0 + arow) * KTOT;
            #pragma unroll
            for (int ii = 0; ii < 16; ++ii) {
                const int kk = (i0 + acol + ii) * 9 + r;
                aw[ii] = wsrc[kk];
                au[ii] = usrc[kk];
            }
        }

        const int hh = ph + (r / 3) - 1;
        const int ww = pw + (r % 3) - 1;
        float bx[16];
        #pragma unroll
        for (int j = 0; j < 16; ++j) bx[j] = 0.f;
        if (((unsigned)hh < 64u) && ((unsigned)ww < 64u)) {
            const float* xsrc = xb + (size_t)(i0 + kh) * NSP + hh * HW + ww;
            #pragma unroll
            for (int j = 0; j < 16; ++j) bx[j] = xsrc[(size_t)j * NSP];
        }

        __syncthreads();

        if (USE_WS) {
            uint4* d = reinterpret_cast<uint4*>(&As[arow * LDT + acol]);
            d[0] = av0; d[1] = av1;
        } else {
            union { unsigned short u16[16]; uint4 v[2]; } tu;
            #pragma unroll
            for (int ii = 0; ii < 16; ++ii)
                tu.u16[ii] = f2bf((au[ii] > PDROP) ? aw[ii] : 0.f);
            uint4* d = reinterpret_cast<uint4*>(&As[arow * LDT + acol]);
            d[0] = tu.v[0]; d[1] = tu.v[1];
        }
        {
            union { unsigned short u16[16]; uint4 v[2]; } tu;
            #pragma unroll
            for (int j = 0; j < 16; ++j) tu.u16[j] = f2bf(bx[j]);
            uint4* d = reinterpret_cast<uint4*>(&Bs[pn * LDT + kh]);
            d[0] = tu.v[0]; d[1] = tu.v[1];
        }

        __syncthreads();

        frag af[4], bfr[4];
        #pragma unroll
        for (int mi = 0; mi < 4; ++mi)
            af[mi] = *reinterpret_cast<const frag*>(&As[a_rd + mi * 16 * LDT]);
        #pragma unroll
        for (int ni = 0; ni < 4; ++ni)
            bfr[ni] = *reinterpret_cast<const frag*>(&Bs[b_rd + ni * 16 * LDT]);
        #pragma unroll
        for (int mi = 0; mi < 4; ++mi)
            #pragma unroll
            for (int ni = 0; ni < 4; ++ni)
                acc[mi][ni] = __builtin_amdgcn_mfma_f32_16x16x32_bf16(
                    af[mi], bfr[ni], acc[mi][ni], 0, 0, 0);
    }

    float* ob = out + (size_t)b * COUT * NSP;
    #pragma unroll
    for (int mi = 0; mi < 4; ++mi) {
        #pragma unroll
        for (int rg = 0; rg < 4; ++rg) {
            const int o = m0 + wm + mi * 16 + q * 4 + rg;
            const float bvv = (u_b[b * COUT + o] > PDROP) ? bias[o] : 0.f;
            float* orow = ob + (size_t)o * NSP + n0 + wn + l15;
            #pragma unroll
            for (int ni = 0; ni < 4; ++ni)
                orow[ni * 16] = acc[mi][ni][rg] + bvv;
        }
    }
}

extern "C" void kernel_launch(void* const* d_in, const int* in_sizes, int n_in,
                              void* d_out, int out_size, void* d_ws, size_t ws_size,
                              hipStream_t stream)
{
    const float* x      = (const float*)d_in[0];
    const float* weight = (const float*)d_in[1];
    const float* bias   = (const float*)d_in[2];
    const float* u_w    = (const float*)d_in[3];
    const float* u_b    = (const float*)d_in[4];
    float* out = (float*)d_out;

    const size_t wt_bytes = (size_t)BATCH * COUT * KTOT * sizeof(unsigned short); // 18.87 MB
    const size_t xt_bytes = (size_t)BATCH * NSP * CIN * sizeof(unsigned short);   // 33.55 MB
    dim3 grid(NSP / 128, COUT / 128, BATCH);   // 32 x 2 x 32 = 2048 blocks

    if (ws_size >= wt_bytes + xt_bytes) {
        unsigned short* wtp = (unsigned short*)d_ws;
        unsigned short* xtp = (unsigned short*)((char*)d_ws + wt_bytes);
        mask_weights<<<BATCH * COUT, 128, 0, stream>>>(weight, u_w, wtp);
        transpose_x<<<dim3(NSP / 64, BATCH), 256, 0, stream>>>(x, xtp);
        conv_v2<<<grid, 256, 0, stream>>>(wtp, xtp, bias, u_b, out);
    } else if (ws_size >= wt_bytes) {
        unsigned short* wtp = (unsigned short*)d_ws;
        mask_weights<<<BATCH * COUT, 128, 0, stream>>>(weight, u_w, wtp);
        conv_fb<true><<<grid, 256, 0, stream>>>(x, weight, bias, u_w, u_b, wtp, out);
    } else {
        conv_fb<false><<<grid, 256, 0, stream>>>(x, weight, bias, u_w, u_b, nullptr, out);
    }
}

// Round 3
// 319.188 us; speedup vs baseline: 1.3200x; 1.3200x over previous
//
#include <hip/hip_runtime.h>
#include <cstdint>
#include <cstddef>

#define CIN   128
#define COUT  256
#define HW    64
#define NSP   4096      // 64*64 spatial
#define KTOT  1152      // CIN*9
#define BATCH 32
#define PDROP 0.2f
#define LDT   40        // fallback conv LDS stride (bf16 elems)

__device__ __forceinline__ unsigned short f2bf(float f) {
    unsigned int u = __builtin_bit_cast(unsigned int, f);
    u += 0x7fffu + ((u >> 16) & 1u);   // round-to-nearest-even
    return (unsigned short)(u >> 16);
}

// 128 B of guaranteed zeros for OOB halo DMA source (.data, never written)
__device__ __align__(16) unsigned short g_zeros[64] = {0};

// async global->LDS, 16 B per lane; LDS dest = wave-uniform base + lane*16
__device__ __forceinline__ void gl_lds16(const unsigned short* g, unsigned short* l) {
    __builtin_amdgcn_global_load_lds(
        (const __attribute__((address_space(1))) unsigned int*)g,
        (__attribute__((address_space(3))) unsigned int*)l,
        16, 0, 0);
}

// ---------------------------------------------------------------------------
// Pre-pass 1: per-sample masked bf16 weights, tap-major: wt[bo][r*128+i]
__global__ __launch_bounds__(128) void mask_weights(
        const float* __restrict__ weight, const float* __restrict__ u_w,
        unsigned short* __restrict__ wt)
{
    __shared__ unsigned short tile[KTOT];
    const int bo = blockIdx.x;                 // b*COUT + o
    const int o  = bo & (COUT - 1);
    const int t  = threadIdx.x;
    const float4* wsrc = reinterpret_cast<const float4*>(weight + (size_t)o  * KTOT);
    const float4* usrc = reinterpret_cast<const float4*>(u_w    + (size_t)bo * KTOT);
    #pragma unroll
    for (int j = 0; j < 3; ++j) {
        const int idx = j * 128 + t;           // 0..287 float4s
        if (idx < KTOT / 4) {
            float4 wv = wsrc[idx];
            float4 uv = usrc[idx];
            const float w4[4] = {wv.x, wv.y, wv.z, wv.w};
            const float u4[4] = {uv.x, uv.y, uv.z, uv.w};
            #pragma unroll
            for (int c = 0; c < 4; ++c) {
                const int ks = idx * 4 + c;    // OIHW flat: ks = i*9 + r
                const int i  = ks / 9;
                const int r  = ks - 9 * i;
                tile[r * CIN + i] = f2bf((u4[c] > PDROP) ? w4[c] : 0.f);
            }
        }
    }
    __syncthreads();
    const uint4* src = reinterpret_cast<const uint4*>(tile);
    uint4* dst = reinterpret_cast<uint4*>(wt + (size_t)bo * KTOT);
    #pragma unroll
    for (int j = 0; j < 2; ++j) {
        const int idx = j * 128 + t;           // 0..143 uint4s
        if (idx < KTOT / 8) dst[idx] = src[idx];
    }
}

// ---------------------------------------------------------------------------
// Pre-pass 2: x NCHW fp32 -> xt[b][hw][ch] bf16 (NHWC).
__global__ __launch_bounds__(256) void transpose_x(
        const float* __restrict__ x, unsigned short* __restrict__ xt)
{
    __shared__ unsigned short tile[64 * 136];  // [hw_loc][ch], stride 136
    const int b   = blockIdx.y;
    const int hw0 = blockIdx.x * 64;
    const int t   = threadIdx.x;
    const int ib  = t >> 4;                    // 0..15
    const int hw4 = (t & 15) * 4;
    #pragma unroll
    for (int j = 0; j < 8; ++j) {
        const int i = ib + 16 * j;             // channel 0..127
        const float4 v = *reinterpret_cast<const float4*>(
            x + ((size_t)(b * CIN + i)) * NSP + hw0 + hw4);
        const float v4[4] = {v.x, v.y, v.z, v.w};
        #pragma unroll
        for (int c = 0; c < 4; ++c)
            tile[(hw4 + c) * 136 + i] = f2bf(v4[c]);
    }
    __syncthreads();
    #pragma unroll
    for (int j = 0; j < 4; ++j) {
        const int idx  = j * 256 + t;          // 0..1023
        const int row  = idx >> 4;             // hw_loc 0..63
        const int part = idx & 15;             // 16 B chunk
        const uint4 v = *reinterpret_cast<const uint4*>(&tile[row * 136 + part * 8]);
        *reinterpret_cast<uint4*>(
            xt + ((size_t)(b * NSP + hw0 + row)) * CIN + part * 8) = v;
    }
}

// ---------------------------------------------------------------------------
// Main conv v3: implicit GEMM, BM=BN=128, BK=64, 18 stages.
// Staging via global_load_lds (16 B/lane DMA, no VGPR round-trip, no spill).
// LDS rows unpadded (64 bf16 = 128 B); XOR chunk swizzle on global addresses
// keeps frag ds_read_b128 at the inherent-minimum bank phases.
__global__ __launch_bounds__(256) void conv_v3(
        const unsigned short* __restrict__ wt,
        const unsigned short* __restrict__ xt,
        const float* __restrict__ bias, const float* __restrict__ u_b,
        float* __restrict__ out)
{
    using frag  = __attribute__((ext_vector_type(8))) short;
    using f32x4 = __attribute__((ext_vector_type(4))) float;

    __shared__ unsigned short As[128 * 64];    // [o_loc][k]  16384 B
    __shared__ unsigned short Bs[128 * 64];    // [p_loc][k]  16384 B

    const int tid  = threadIdx.x;
    const int lane = tid & 63;
    const int q    = lane >> 4;
    const int l15  = lane & 15;
    const int wv   = tid >> 6;
    const int wm   = (wv >> 1) * 64;
    const int wn   = (wv & 1) * 64;

    const int b  = blockIdx.z;
    const int m0 = blockIdx.y * 128;
    const int n0 = blockIdx.x * 128;

    // DMA staging map: per wave-instruction j, 64 lanes cover 8 rows x 128 B.
    const int r8 = lane >> 3;                  // row-in-group 0..7
    const int p8 = lane & 7;                   // phys 16 B chunk 0..7
    const int cx = p8 ^ r8;                    // logical chunk (self-inverse swizzle)

    const unsigned short* wtb = wt + (size_t)(b * COUT + m0) * KTOT;
    const unsigned short* xtb = xt + (size_t)b * NSP * CIN;

    // A global pointers per j (advance by 64 each stage)
    const unsigned short* gA[4];
    int py[4], px[4];
    #pragma unroll
    for (int j = 0; j < 4; ++j) {
        const int row = wv * 32 + j * 8 + r8;  // 0..127
        gA[j] = wtb + (size_t)row * KTOT + cx * 8;
        const int p_sp = n0 + row;
        py[j] = p_sp >> 6;
        px[j] = p_sp & 63;
    }
    // wave-uniform LDS bases per j
    unsigned short* ldsA[4];
    unsigned short* ldsB[4];
    #pragma unroll
    for (int j = 0; j < 4; ++j) {
        ldsA[j] = &As[(wv * 32 + j * 8) * 64];
        ldsB[j] = &Bs[(wv * 32 + j * 8) * 64];
    }

    f32x4 acc[4][4];
    #pragma unroll
    for (int i = 0; i < 4; ++i)
        #pragma unroll
        for (int j = 0; j < 4; ++j)
            acc[i][j] = (f32x4){0.f, 0.f, 0.f, 0.f};

    // frag-read constants (swizzled)
    const int l7 = l15 & 7;
    const int physk0 = (q)     ^ l7;           // ki=0 chunk
    const int physk1 = (4 + q) ^ l7;           // ki=1 chunk
    const int a_base = (wm + l15) * 64;
    const int b_base = (wn + l15) * 64;

    for (int s = 0; s < 18; ++s) {
        const int r  = s >> 1;                 // tap 0..8 (uniform)
        const int i0 = (s & 1) * 64;           // channel base
        const int dy = r / 3 - 1;
        const int dx = r - 3 * (r / 3) - 1;

        __syncthreads();                       // prior stage's frag reads done

        #pragma unroll
        for (int j = 0; j < 4; ++j) {
            gl_lds16(gA[j], ldsA[j]);
            gA[j] += 64;
            const int hh = py[j] + dy;
            const int ww = px[j] + dx;
            const bool valid = ((unsigned)hh < 64u) && ((unsigned)ww < 64u);
            const unsigned short* srcB = valid
                ? xtb + (size_t)(hh * HW + ww) * CIN + i0 + cx * 8
                : g_zeros + p8 * 8;
            gl_lds16(srcB, ldsB[j]);
        }

        __syncthreads();                       // drains vmcnt(0): LDS ready

        #pragma unroll
        for (int ki = 0; ki < 2; ++ki) {
            const int pk = ki ? physk1 : physk0;
            frag af[4], bfr[4];
            #pragma unroll
            for (int mi = 0; mi < 4; ++mi)
                af[mi] = *reinterpret_cast<const frag*>(
                    &As[a_base + mi * 1024 + pk * 8]);
            #pragma unroll
            for (int ni = 0; ni < 4; ++ni)
                bfr[ni] = *reinterpret_cast<const frag*>(
                    &Bs[b_base + ni * 1024 + pk * 8]);
            #pragma unroll
            for (int mi = 0; mi < 4; ++mi)
                #pragma unroll
                for (int ni = 0; ni < 4; ++ni)
                    acc[mi][ni] = __builtin_amdgcn_mfma_f32_16x16x32_bf16(
                        af[mi], bfr[ni], acc[mi][ni], 0, 0, 0);
        }
    }

    // ---- epilogue: D row=(q*4+reg), col=l15 ; add dropped-out bias
    float* ob = out + (size_t)b * COUT * NSP;
    #pragma unroll
    for (int mi = 0; mi < 4; ++mi) {
        #pragma unroll
        for (int rg = 0; rg < 4; ++rg) {
            const int o  = m0 + wm + mi * 16 + q * 4 + rg;
            const float bvv = (u_b[b * COUT + o] > PDROP) ? bias[o] : 0.f;
            float* orow = ob + (size_t)o * NSP + n0 + wn + l15;
            #pragma unroll
            for (int ni = 0; ni < 4; ++ni)
                orow[ni * 16] = acc[mi][ni][rg] + bvv;
        }
    }
}

// ---------------------------------------------------------------------------
// Fallback (round-1 kernel): used only if workspace is too small.
template<bool USE_WS>
__global__ __launch_bounds__(256) void conv_fb(
        const float* __restrict__ x, const float* __restrict__ weight,
        const float* __restrict__ bias, const float* __restrict__ u_w,
        const float* __restrict__ u_b, const unsigned short* __restrict__ wt,
        float* __restrict__ out)
{
    using frag  = __attribute__((ext_vector_type(8))) short;
    using f32x4 = __attribute__((ext_vector_type(4))) float;

    __shared__ unsigned short As[128 * LDT];
    __shared__ unsigned short Bs[128 * LDT];

    const int tid  = threadIdx.x;
    const int lane = tid & 63;
    const int q    = lane >> 4;
    const int l15  = lane & 15;
    const int wv   = tid >> 6;
    const int wm   = (wv >> 1) * 64;
    const int wn   = (wv & 1) * 64;

    const int b  = blockIdx.z;
    const int m0 = blockIdx.y * 128;
    const int n0 = blockIdx.x * 128;

    const int arow = tid >> 1;
    const int acol = (tid & 1) * 16;
    const int pn = tid & 127;
    const int kh = (tid >> 7) * 16;
    const int p  = n0 + pn;
    const int ph = p >> 6;
    const int pw = p & 63;

    const float* xb = x + (size_t)b * CIN * NSP;

    f32x4 acc[4][4];
    #pragma unroll
    for (int i = 0; i < 4; ++i)
        #pragma unroll
        for (int j = 0; j < 4; ++j)
            acc[i][j] = (f32x4){0.f, 0.f, 0.f, 0.f};

    const int a_rd = (wm + l15) * LDT + q * 8;
    const int b_rd = (wn + l15) * LDT + q * 8;

    for (int s = 0; s < 36; ++s) {
        const int r  = s >> 2;
        const int i0 = (s & 3) * 32;
        const int k0 = s * 32;

        uint4 av0, av1;
        float aw[16], au[16];
        if (USE_WS) {
            const uint4* src = reinterpret_cast<const uint4*>(
                wt + ((size_t)(b * COUT + m0 + arow)) * KTOT + k0 + acol);
            av0 = src[0];
            av1 = src[1];
        } else {
            const float* wsrc = weight + (size_t)(m0 + arow) * KTOT;
            const float* usrc = u_w + (size_t)(b * COUT + m0 + arow) * KTOT;
            #pragma unroll
            for (int ii = 0; ii < 16; ++ii) {
                const int kk = (i0 + acol + ii) * 9 + r;
                aw[ii] = wsrc[kk];
                au[ii] = usrc[kk];
            }
        }

        const int hh = ph + (r / 3) - 1;
        const int ww = pw + (r % 3) - 1;
        float bx[16];
        #pragma unroll
        for (int j = 0; j < 16; ++j) bx[j] = 0.f;
        if (((unsigned)hh < 64u) && ((unsigned)ww < 64u)) {
            const float* xsrc = xb + (size_t)(i0 + kh) * NSP + hh * HW + ww;
            #pragma unroll
            for (int j = 0; j < 16; ++j) bx[j] = xsrc[(size_t)j * NSP];
        }

        __syncthreads();

        if (USE_WS) {
            uint4* d = reinterpret_cast<uint4*>(&As[arow * LDT + acol]);
            d[0] = av0; d[1] = av1;
        } else {
            union { unsigned short u16[16]; uint4 v[2]; } tu;
            #pragma unroll
            for (int ii = 0; ii < 16; ++ii)
                tu.u16[ii] = f2bf((au[ii] > PDROP) ? aw[ii] : 0.f);
            uint4* d = reinterpret_cast<uint4*>(&As[arow * LDT + acol]);
            d[0] = tu.v[0]; d[1] = tu.v[1];
        }
        {
            union { unsigned short u16[16]; uint4 v[2]; } tu;
            #pragma unroll
            for (int j = 0; j < 16; ++j) tu.u16[j] = f2bf(bx[j]);
            uint4* d = reinterpret_cast<uint4*>(&Bs[pn * LDT + kh]);
            d[0] = tu.v[0]; d[1] = tu.v[1];
        }

        __syncthreads();

        frag af[4], bfr[4];
        #pragma unroll
        for (int mi = 0; mi < 4; ++mi)
            af[mi] = *reinterpret_cast<const frag*>(&As[a_rd + mi * 16 * LDT]);
        #pragma unroll
        for (int ni = 0; ni < 4; ++ni)
            bfr[ni] = *reinterpret_cast<const frag*>(&Bs[b_rd + ni * 16 * LDT]);
        #pragma unroll
        for (int mi = 0; mi < 4; ++mi)
            #pragma unroll
            for (int ni = 0; ni < 4; ++ni)
                acc[mi][ni] = __builtin_amdgcn_mfma_f32_16x16x32_bf16(
                    af[mi], bfr[ni], acc[mi][ni], 0, 0, 0);
    }

    float* ob = out + (size_t)b * COUT * NSP;
    #pragma unroll
    for (int mi = 0; mi < 4; ++mi) {
        #pragma unroll
        for (int rg = 0; rg < 4; ++rg) {
            const int o = m0 + wm + mi * 16 + q * 4 + rg;
            const float bvv = (u_b[b * COUT + o] > PDROP) ? bias[o] : 0.f;
            float* orow = ob + (size_t)o * NSP + n0 + wn + l15;
            #pragma unroll
            for (int ni = 0; ni < 4; ++ni)
                orow[ni * 16] = acc[mi][ni][rg] + bvv;
        }
    }
}

extern "C" void kernel_launch(void* const* d_in, const int* in_sizes, int n_in,
                              void* d_out, int out_size, void* d_ws, size_t ws_size,
                              hipStream_t stream)
{
    const float* x      = (const float*)d_in[0];
    const float* weight = (const float*)d_in[1];
    const float* bias   = (const float*)d_in[2];
    const float* u_w    = (const float*)d_in[3];
    const float* u_b    = (const float*)d_in[4];
    float* out = (float*)d_out;

    const size_t wt_bytes = (size_t)BATCH * COUT * KTOT * sizeof(unsigned short); // 18.87 MB
    const size_t xt_bytes = (size_t)BATCH * NSP * CIN * sizeof(unsigned short);   // 33.55 MB
    dim3 grid(NSP / 128, COUT / 128, BATCH);   // 32 x 2 x 32 = 2048 blocks

    if (ws_size >= wt_bytes + xt_bytes) {
        unsigned short* wtp = (unsigned short*)d_ws;
        unsigned short* xtp = (unsigned short*)((char*)d_ws + wt_bytes);
        mask_weights<<<BATCH * COUT, 128, 0, stream>>>(weight, u_w, wtp);
        transpose_x<<<dim3(NSP / 64, BATCH), 256, 0, stream>>>(x, xtp);
        conv_v3<<<grid, 256, 0, stream>>>(wtp, xtp, bias, u_b, out);
    } else if (ws_size >= wt_bytes) {
        unsigned short* wtp = (unsigned short*)d_ws;
        mask_weights<<<BATCH * COUT, 128, 0, stream>>>(weight, u_w, wtp);
        conv_fb<true><<<grid, 256, 0, stream>>>(x, weight, bias, u_w, u_b, wtp, out);
    } else {
        conv_fb<false><<<grid, 256, 0, stream>>>(x, weight, bias, u_w, u_b, nullptr, out);
    }
}

// Round 4
// 284.111 us; speedup vs baseline: 1.4830x; 1.1235x over previous
//
#include <hip/hip_runtime.h>
#include <cstdint>
#include <cstddef>

#define CIN   128
#define COUT  256
#define HW    64
#define NSP   4096      // 64*64 spatial
#define KTOT  1152      // CIN*9
#define BATCH 32
#define PDROP 0.2f
#define LDT   40        // fallback conv LDS stride (bf16 elems)

__device__ __forceinline__ unsigned short f2bf(float f) {
    unsigned int u = __builtin_bit_cast(unsigned int, f);
    u += 0x7fffu + ((u >> 16) & 1u);   // round-to-nearest-even
    return (unsigned short)(u >> 16);
}

// 128 B of guaranteed zeros for OOB halo DMA source (never written)
__device__ __align__(16) unsigned short g_zeros[64] = {0};

// async global->LDS, 16 B per lane; LDS dest = wave-uniform base + lane*16
__device__ __forceinline__ void gl_lds16(const unsigned short* g, unsigned short* l) {
    __builtin_amdgcn_global_load_lds(
        (const __attribute__((address_space(1))) unsigned int*)g,
        (__attribute__((address_space(3))) unsigned int*)l,
        16, 0, 0);
}

// ---------------------------------------------------------------------------
// Fused pre-pass (single launch):
//  blocks [0,4096):   per-sample masked bf16 weights, tap-major wt[bo][r*128+i]
//                     (2 bo per block)
//  blocks [4096,6144): x NCHW fp32 -> xt[b][hw][ch] bf16 (NHWC)
__global__ __launch_bounds__(256) void prepass(
        const float* __restrict__ weight, const float* __restrict__ u_w,
        const float* __restrict__ x,
        unsigned short* __restrict__ wt, unsigned short* __restrict__ xt)
{
    __shared__ unsigned short sh[8704];            // max(2*1152, 64*136)
    const int t256 = threadIdx.x;

    if (blockIdx.x < 4096) {
        const int half = t256 >> 7;                // 0/1: which bo
        const int t    = t256 & 127;
        const int bo   = blockIdx.x * 2 + half;    // b*COUT + o
        const int o    = bo & (COUT - 1);
        unsigned short* tile = sh + half * KTOT;
        const float4* wsrc = reinterpret_cast<const float4*>(weight + (size_t)o  * KTOT);
        const float4* usrc = reinterpret_cast<const float4*>(u_w    + (size_t)bo * KTOT);
        #pragma unroll
        for (int j = 0; j < 3; ++j) {
            const int idx = j * 128 + t;           // 0..287 float4s
            if (idx < KTOT / 4) {
                float4 wv = wsrc[idx];
                float4 uv = usrc[idx];
                const float w4[4] = {wv.x, wv.y, wv.z, wv.w};
                const float u4[4] = {uv.x, uv.y, uv.z, uv.w};
                #pragma unroll
                for (int c = 0; c < 4; ++c) {
                    const int ks = idx * 4 + c;    // OIHW flat: ks = i*9 + r
                    const int i  = ks / 9;
                    const int r  = ks - 9 * i;
                    tile[r * CIN + i] = f2bf((u4[c] > PDROP) ? w4[c] : 0.f);
                }
            }
        }
        __syncthreads();
        const uint4* src = reinterpret_cast<const uint4*>(tile);
        uint4* dst = reinterpret_cast<uint4*>(wt + (size_t)bo * KTOT);
        #pragma unroll
        for (int j = 0; j < 2; ++j) {
            const int idx = j * 128 + t;           // 0..143 uint4s
            if (idx < KTOT / 8) dst[idx] = src[idx];
        }
    } else {
        const int bidx = blockIdx.x - 4096;
        const int b    = bidx >> 6;
        const int hw0  = (bidx & 63) * 64;
        const int ib   = t256 >> 4;                // 0..15
        const int hw4  = (t256 & 15) * 4;
        #pragma unroll
        for (int j = 0; j < 8; ++j) {
            const int i = ib + 16 * j;             // channel 0..127
            const float4 v = *reinterpret_cast<const float4*>(
                x + ((size_t)(b * CIN + i)) * NSP + hw0 + hw4);
            const float v4[4] = {v.x, v.y, v.z, v.w};
            #pragma unroll
            for (int c = 0; c < 4; ++c)
                sh[(hw4 + c) * 136 + i] = f2bf(v4[c]);
        }
        __syncthreads();
        #pragma unroll
        for (int j = 0; j < 4; ++j) {
            const int idx  = j * 256 + t256;       // 0..1023
            const int row  = idx >> 4;             // hw_loc 0..63
            const int part = idx & 15;             // 16 B chunk
            const uint4 v = *reinterpret_cast<const uint4*>(&sh[row * 136 + part * 8]);
            *reinterpret_cast<uint4*>(
                xt + ((size_t)(b * NSP + hw0 + row)) * CIN + part * 8) = v;
        }
    }
}

// ---------------------------------------------------------------------------
// Main conv v4: implicit GEMM with LDS-resident x-tile.
// BM=BN=128. Per ch-slab (64 ch): DMA X[4 rows][66 cols][64 ch] once, then
// 9 taps x (DMA A-tile 128x64, 2 MFMA k-steps) reading shifted windows of X.
// XOR chunk swizzle on the DMA *source* addresses keeps all frag ds_read_b128
// at the free 2-way bank aliasing with zero padding (DMA dest must be
// contiguous wave-uniform base + lane*16).
__global__ __launch_bounds__(256, 3) void conv_v4(
        const unsigned short* __restrict__ wt,
        const unsigned short* __restrict__ xt,
        const float* __restrict__ bias, const float* __restrict__ u_b,
        float* __restrict__ out)
{
    using frag  = __attribute__((ext_vector_type(8))) short;
    using f32x4 = __attribute__((ext_vector_type(4))) float;

    __shared__ unsigned short Xs[4 * 66 * 64];     // 33792 B resident x-tile
    __shared__ unsigned short As[128 * 64];        // 16384 B per-tap A-tile

    const int tid  = threadIdx.x;
    const int lane = tid & 63;
    const int q    = lane >> 4;
    const int l15  = lane & 15;
    const int wv   = tid >> 6;
    const int wm   = (wv >> 1) * 64;
    const int wn   = (wv & 1) * 64;
    const int wnrow = wn >> 6;                     // 0 or 1: tile spatial row

    const int b   = blockIdx.z;
    const int m0  = blockIdx.y * 128;
    const int n0  = blockIdx.x * 128;
    const int ph0 = n0 >> 6;                       // first global image row

    const unsigned short* wtb = wt + (size_t)(b * COUT + m0) * KTOT;
    const unsigned short* xtb = xt + (size_t)b * NSP * CIN;

    // ---- A-DMA map (as v3): lane -> (row r8 in group of 8, phys chunk p8)
    const int r8 = lane >> 3;
    const int p8 = lane & 7;
    const int cx = p8 ^ r8;                        // logical chunk (swizzle)
    const unsigned short* gA[4];
    unsigned short* ldsA[4];
    #pragma unroll
    for (int j = 0; j < 4; ++j) {
        const int row = wv * 32 + j * 8 + r8;      // 0..127
        gA[j]   = wtb + (size_t)row * KTOT + cx * 8;
        ldsA[j] = &As[(wv * 32 + j * 8) * 64];
    }

    // ---- X-DMA map: wave wv stages X row rr=wv (global row ph0-1+wv).
    // lane L -> col offset L>>3, phys chunk L&7; logical chunk is XOR'd by cc&7
    const int kcl = (lane & 7) ^ ((1 + (lane >> 3)) & 7);
    const int xsrc_lane = (lane >> 3) * CIN + kcl * 8;   // u16 offset in xt row
    const int hhx = ph0 - 1 + wv;
    const bool vrow = ((unsigned)hhx < 64u);
    unsigned short* const xdst = &Xs[(wv * 66 + 1) * 64];

    // ---- frag-read constants
    const int l7 = l15 & 7;
    const int physk0 = q ^ l7;                     // A ki=0 phys chunk
    const int physk1 = (4 + q) ^ l7;               // A ki=1
    const int a_base = (wm + l15) * 64;
    int xoff[4];                                   // (ni*16 + l15 + 1)*64
    #pragma unroll
    for (int ni = 0; ni < 4; ++ni) xoff[ni] = (ni * 16 + l15 + 1) * 64;
    int xr[3][2];                                  // phys*8 per (dx+1, ki)
    #pragma unroll
    for (int dxi = 0; dxi < 3; ++dxi)
        #pragma unroll
        for (int ki = 0; ki < 2; ++ki)
            xr[dxi][ki] = ((ki * 4 + q) ^ ((l15 + dxi) & 7)) * 8;

    f32x4 acc[4][4];
    #pragma unroll
    for (int i = 0; i < 4; ++i)
        #pragma unroll
        for (int j = 0; j < 4; ++j)
            acc[i][j] = (f32x4){0.f, 0.f, 0.f, 0.f};

    // ---- zero the column-halo cells of Xs once (cc=0 and cc=65, all 4 rows)
    {
        const int cell = tid >> 5;                 // 0..7
        const int rr   = cell >> 1;
        const int cc   = (cell & 1) ? 65 : 0;
        *reinterpret_cast<unsigned int*>(
            &Xs[(rr * 66 + cc) * 64 + (tid & 31) * 2]) = 0u;
    }

    #pragma unroll
    for (int s2 = 0; s2 < 2; ++s2) {
        const int i0 = s2 * 64;                    // channel-slab base

        __syncthreads();                           // protect Xs/As from prior reads

        // ---- X-tile DMA: 8 x 1KB per wave (row rr=wv, cols 0..63 -> cc 1..64)
        {
            const unsigned short* sx = vrow
                ? xtb + (size_t)hhx * HW * CIN + i0 + xsrc_lane
                : g_zeros;
            #pragma unroll
            for (int g = 0; g < 8; ++g)
                gl_lds16(vrow ? (sx + g * 8 * CIN) : sx, xdst + g * 512);
        }

        #pragma unroll
        for (int tap = 0; tap < 9; ++tap) {
            const int dy  = tap / 3 - 1;
            const int dx  = tap - 3 * (tap / 3) - 1;
            const int dxi = dx + 1;

            if (tap) __syncthreads();              // protect As from prior reads

            // ---- A-tile DMA for this tap (4 x 1KB per wave)
            const int k0 = tap * 128 + i0;
            #pragma unroll
            for (int j = 0; j < 4; ++j)
                gl_lds16(gA[j] + k0, ldsA[j]);

            __syncthreads();                       // drain DMA: As (and Xs) ready

            const int cb = (wnrow + dy + 1) * 4224 + dx * 64;  // 66*64 = 4224

            #pragma unroll
            for (int ki = 0; ki < 2; ++ki) {
                const int pk = ki ? physk1 : physk0;
                frag af[4], bfr[4];
                #pragma unroll
                for (int mi = 0; mi < 4; ++mi)
                    af[mi] = *reinterpret_cast<const frag*>(
                        &As[a_base + mi * 1024 + pk * 8]);
                #pragma unroll
                for (int ni = 0; ni < 4; ++ni)
                    bfr[ni] = *reinterpret_cast<const frag*>(
                        &Xs[cb + xoff[ni] + xr[dxi][ki]]);
                #pragma unroll
                for (int mi = 0; mi < 4; ++mi)
                    #pragma unroll
                    for (int ni = 0; ni < 4; ++ni)
                        acc[mi][ni] = __builtin_amdgcn_mfma_f32_16x16x32_bf16(
                            af[mi], bfr[ni], acc[mi][ni], 0, 0, 0);
            }
        }
    }

    // ---- epilogue: D row=(q*4+reg), col=l15 ; add dropped-out bias
    float* ob = out + (size_t)b * COUT * NSP;
    #pragma unroll
    for (int mi = 0; mi < 4; ++mi) {
        #pragma unroll
        for (int rg = 0; rg < 4; ++rg) {
            const int o  = m0 + wm + mi * 16 + q * 4 + rg;
            const float bvv = (u_b[b * COUT + o] > PDROP) ? bias[o] : 0.f;
            float* orow = ob + (size_t)o * NSP + n0 + wn + l15;
            #pragma unroll
            for (int ni = 0; ni < 4; ++ni)
                orow[ni * 16] = acc[mi][ni][rg] + bvv;
        }
    }
}

// ---------------------------------------------------------------------------
// Fallback (round-1 kernel): used only if workspace is too small.
template<bool USE_WS>
__global__ __launch_bounds__(256) void conv_fb(
        const float* __restrict__ x, const float* __restrict__ weight,
        const float* __restrict__ bias, const float* __restrict__ u_w,
        const float* __restrict__ u_b, const unsigned short* __restrict__ wt,
        float* __restrict__ out)
{
    using frag  = __attribute__((ext_vector_type(8))) short;
    using f32x4 = __attribute__((ext_vector_type(4))) float;

    __shared__ unsigned short As[128 * LDT];
    __shared__ unsigned short Bs[128 * LDT];

    const int tid  = threadIdx.x;
    const int lane = tid & 63;
    const int q    = lane >> 4;
    const int l15  = lane & 15;
    const int wv   = tid >> 6;
    const int wm   = (wv >> 1) * 64;
    const int wn   = (wv & 1) * 64;

    const int b  = blockIdx.z;
    const int m0 = blockIdx.y * 128;
    const int n0 = blockIdx.x * 128;

    const int arow = tid >> 1;
    const int acol = (tid & 1) * 16;
    const int pn = tid & 127;
    const int kh = (tid >> 7) * 16;
    const int p  = n0 + pn;
    const int ph = p >> 6;
    const int pw = p & 63;

    const float* xb = x + (size_t)b * CIN * NSP;

    f32x4 acc[4][4];
    #pragma unroll
    for (int i = 0; i < 4; ++i)
        #pragma unroll
        for (int j = 0; j < 4; ++j)
            acc[i][j] = (f32x4){0.f, 0.f, 0.f, 0.f};

    const int a_rd = (wm + l15) * LDT + q * 8;
    const int b_rd = (wn + l15) * LDT + q * 8;

    for (int s = 0; s < 36; ++s) {
        const int r  = s >> 2;
        const int i0 = (s & 3) * 32;
        const int k0 = s * 32;

        uint4 av0, av1;
        float aw[16], au[16];
        if (USE_WS) {
            const uint4* src = reinterpret_cast<const uint4*>(
                wt + ((size_t)(b * COUT + m0 + arow)) * KTOT + k0 + acol);
            av0 = src[0];
            av1 = src[1];
        } else {
            const float* wsrc = weight + (size_t)(m0 + arow) * KTOT;
            const float* usrc = u_w + (size_t)(b * COUT + m0 + arow) * KTOT;
            #pragma unroll
            for (int ii = 0; ii < 16; ++ii) {
                const int kk = (i0 + acol + ii) * 9 + r;
                aw[ii] = wsrc[kk];
                au[ii] = usrc[kk];
            }
        }

        const int hh = ph + (r / 3) - 1;
        const int ww = pw + (r % 3) - 1;
        float bx[16];
        #pragma unroll
        for (int j = 0; j < 16; ++j) bx[j] = 0.f;
        if (((unsigned)hh < 64u) && ((unsigned)ww < 64u)) {
            const float* xsrc = xb + (size_t)(i0 + kh) * NSP + hh * HW + ww;
            #pragma unroll
            for (int j = 0; j < 16; ++j) bx[j] = xsrc[(size_t)j * NSP];
        }

        __syncthreads();

        if (USE_WS) {
            uint4* d = reinterpret_cast<uint4*>(&As[arow * LDT + acol]);
            d[0] = av0; d[1] = av1;
        } else {
            union { unsigned short u16[16]; uint4 v[2]; } tu;
            #pragma unroll
            for (int ii = 0; ii < 16; ++ii)
                tu.u16[ii] = f2bf((au[ii] > PDROP) ? aw[ii] : 0.f);
            uint4* d = reinterpret_cast<uint4*>(&As[arow * LDT + acol]);
            d[0] = tu.v[0]; d[1] = tu.v[1];
        }
        {
            union { unsigned short u16[16]; uint4 v[2]; } tu;
            #pragma unroll
            for (int j = 0; j < 16; ++j) tu.u16[j] = f2bf(bx[j]);
            uint4* d = reinterpret_cast<uint4*>(&Bs[pn * LDT + kh]);
            d[0] = tu.v[0]; d[1] = tu.v[1];
        }

        __syncthreads();

        frag af[4], bfr[4];
        #pragma unroll
        for (int mi = 0; mi < 4; ++mi)
            af[mi] = *reinterpret_cast<const frag*>(&As[a_rd + mi * 16 * LDT]);
        #pragma unroll
        for (int ni = 0; ni < 4; ++ni)
            bfr[ni] = *reinterpret_cast<const frag*>(&Bs[b_rd + ni * 16 * LDT]);
        #pragma unroll
        for (int mi = 0; mi < 4; ++mi)
            #pragma unroll
            for (int ni = 0; ni < 4; ++ni)
                acc[mi][ni] = __builtin_amdgcn_mfma_f32_16x16x32_bf16(
                    af[mi], bfr[ni], acc[mi][ni], 0, 0, 0);
    }

    float* ob = out + (size_t)b * COUT * NSP;
    #pragma unroll
    for (int mi = 0; mi < 4; ++mi) {
        #pragma unroll
        for (int rg = 0; rg < 4; ++rg) {
            const int o = m0 + wm + mi * 16 + q * 4 + rg;
            const float bvv = (u_b[b * COUT + o] > PDROP) ? bias[o] : 0.f;
            float* orow = ob + (size_t)o * NSP + n0 + wn + l15;
            #pragma unroll
            for (int ni = 0; ni < 4; ++ni)
                orow[ni * 16] = acc[mi][ni][rg] + bvv;
        }
    }
}

extern "C" void kernel_launch(void* const* d_in, const int* in_sizes, int n_in,
                              void* d_out, int out_size, void* d_ws, size_t ws_size,
                              hipStream_t stream)
{
    const float* x      = (const float*)d_in[0];
    const float* weight = (const float*)d_in[1];
    const float* bias   = (const float*)d_in[2];
    const float* u_w    = (const float*)d_in[3];
    const float* u_b    = (const float*)d_in[4];
    float* out = (float*)d_out;

    const size_t wt_bytes = (size_t)BATCH * COUT * KTOT * sizeof(unsigned short); // 18.87 MB
    const size_t xt_bytes = (size_t)BATCH * NSP * CIN * sizeof(unsigned short);   // 33.55 MB
    dim3 grid(NSP / 128, COUT / 128, BATCH);   // 32 x 2 x 32 = 2048 blocks

    if (ws_size >= wt_bytes + xt_bytes) {
        unsigned short* wtp = (unsigned short*)d_ws;
        unsigned short* xtp = (unsigned short*)((char*)d_ws + wt_bytes);
        prepass<<<4096 + 2048, 256, 0, stream>>>(weight, u_w, x, wtp, xtp);
        conv_v4<<<grid, 256, 0, stream>>>(wtp, xtp, bias, u_b, out);
    } else if (ws_size >= wt_bytes) {
        unsigned short* wtp = (unsigned short*)d_ws;
        // reuse prepass weight half only
        prepass<<<4096, 256, 0, stream>>>(weight, u_w, x, wtp, nullptr);
        conv_fb<true><<<grid, 256, 0, stream>>>(x, weight, bias, u_w, u_b, wtp, out);
    } else {
        conv_fb<false><<<grid, 256, 0, stream>>>(x, weight, bias, u_w, u_b, nullptr, out);
    }
}